// Round 3
// baseline (322.096 us; speedup 1.0000x reference)
//
#include <hip/hip_runtime.h>
#include <hip/hip_bf16.h>
#include <math.h>

#define NPTS   65536
#define NS     16
#define WID    128
#define NHID   3
#define CAP    24576
#define ROWB   272              // bytes per point-row in LDS h tile (128 f16 + 16B pad)
#define CZ     -25.33f          // ln(1e-11): drop (point,s) when min window logit below this

// ws layout:
//   [0,64)                     counts[16]
//   [OFF_IDX, +1.50MB)         idx buckets
//   [OFF_WF,  +1.50MB)         f16 hidden-weight MFMA fragments
//   [OFF_WO,  +64KB)           f16 output-weight row-0 MFMA fragments
#define OFF_IDX 256
#define OFF_WF  (OFF_IDX + NS * CAP * 4)
#define OFF_WO  (OFF_WF + NS * NHID * WID * WID * 2)

typedef _Float16 f16x8 __attribute__((ext_vector_type(8)));
typedef _Float16 f16x4 __attribute__((ext_vector_type(4)));
typedef float    f32x4 __attribute__((ext_vector_type(4)));

// tanh(x) = 1 - 2/(exp2(x*2*log2e)+1); exp2 saturates cleanly so no clamp needed
__device__ __forceinline__ float tanh5(float x) {
    float e = __builtin_amdgcn_exp2f(x * 2.8853900817779268f);
    float r = __builtin_amdgcn_rcpf(e + 1.f);
    return fmaf(-2.f, r, 1.f);
}
__device__ __forceinline__ float sigmf(float z) {
    float e = __builtin_amdgcn_exp2f(-z * 1.4426950408889634f);
    return __builtin_amdgcn_rcpf(1.f + e);
}

// fused: zero out/counts + prepack WF (hidden) + prepack WoutF (output row-0 frags)
__global__ void init_kernel(float* __restrict__ out, int* __restrict__ counts,
                            const float* __restrict__ Wh, _Float16* __restrict__ WF,
                            const float* __restrict__ Wout, _Float16* __restrict__ WoutF) {
    int b = blockIdx.x, t = threadIdx.x;
    if (b < 256) {
        out[b * 256 + t] = 0.f;
        if (b == 0 && t < NS) counts[t] = 0;
    } else if (b < 640) {
        // WF frag g = ((sl*8 + vt)*4 + kk)*64 + lane holds
        // Wh[sl][v = vt*16 + (lane&15)][w = kk*32 + (lane>>4)*8 .. +7]
        int g = (b - 256) * 256 + t;
        int sl = g >> 11, r = g & 2047;
        int vt = r >> 8, kk = (r >> 6) & 3, lane = r & 63;
        int v = vt * 16 + (lane & 15);
        int w0 = kk * 32 + (lane >> 4) * 8;
        const float* src = Wh + (sl << 14) + v * WID + w0;
        float4 a = *(const float4*)src;
        float4 c = *(const float4*)(src + 4);
        f16x8 o;
        o[0] = (_Float16)a.x; o[1] = (_Float16)a.y; o[2] = (_Float16)a.z; o[3] = (_Float16)a.w;
        o[4] = (_Float16)c.x; o[5] = (_Float16)c.y; o[6] = (_Float16)c.z; o[7] = (_Float16)c.w;
        ((f16x8*)WF)[g] = o;
    } else {
        // WoutF frag g = (s*4 + kk)*64 + lane: A[row=lane&15][k=kk*32+(lane>>4)*8..+7],
        // only row 0 nonzero = Wout[s][k]
        int g = (b - 640) * 256 + t;          // 4096 frags
        int s = g >> 8, kk = (g >> 6) & 3, lane = g & 63;
        f16x8 o = (f16x8)(_Float16)0.f;
        if ((lane & 15) == 0) {
            int w0 = kk * 32 + (lane >> 4) * 8;
            const float* src = Wout + s * WID + w0;
            float4 a = *(const float4*)src;
            float4 c = *(const float4*)(src + 4);
            o[0] = (_Float16)a.x; o[1] = (_Float16)a.y; o[2] = (_Float16)a.z; o[3] = (_Float16)a.w;
            o[4] = (_Float16)c.x; o[5] = (_Float16)c.y; o[6] = (_Float16)c.z; o[7] = (_Float16)c.w;
        }
        ((f16x8*)WoutF)[g] = o;
    }
}

__global__ void bucket_kernel(const float* __restrict__ x,
                              const float* __restrict__ mu_min, const float* __restrict__ sd_min,
                              const float* __restrict__ mu_max, const float* __restrict__ sd_max,
                              int* counts, int* __restrict__ idx) {
    int t = threadIdx.x;
    int n = blockIdx.x * 256 + t;
    float xv = x[n];
    int lane = t & 63;
    unsigned long long ltmask = (1ULL << lane) - 1ULL;
    #pragma unroll
    for (int s = 0; s < NS; ++s) {
        float z1 = __fdividef(xv - mu_min[s], sd_min[s]);
        float z2 = __fdividef(mu_max[s] - xv, sd_max[s]);
        bool m = (z1 > CZ) && (z2 > CZ);
        unsigned long long mk = __ballot(m);
        int cnt = __popcll(mk);
        int pos = __popcll(mk & ltmask);
        int bs = 0;
        if (lane == 0 && cnt) bs = atomicAdd(&counts[s], cnt);
        bs = __shfl(bs, 0);
        int g = bs + pos;
        if (m && g < CAP) idx[s * CAP + g] = n;
    }
}

__global__ __launch_bounds__(256, 4) void mlp_kernel(
        const float* __restrict__ x,
        const float* __restrict__ W0,   const float* __restrict__ b0,
        const _Float16* __restrict__ WF, const float* __restrict__ bh,
        const _Float16* __restrict__ WoutF, const float* __restrict__ bout,
        const float* __restrict__ centres, const float* __restrict__ scales,
        const float* __restrict__ mu_min,  const float* __restrict__ sd_min,
        const float* __restrict__ mu_max,  const float* __restrict__ sd_max,
        const int* __restrict__ counts, const int* __restrict__ idx,
        float* __restrict__ out) {
    __shared__ __align__(16) char hbuf[2][64 * ROWB];   // ping-pong [p][v] f16, 272B rows
    __shared__ float xi_s[64], wm_s[64];
    __shared__ int   nn_s[64];

    int s = blockIdx.x;
    int cnt = counts[s]; if (cnt > CAP) cnt = CAP;
    int base = blockIdx.y * 64;
    if (base >= cnt) return;               // uniform early-out before any barrier
    int t = threadIdx.x;

    if (t < 64) {
        int p = base + t;
        float xi = 0.f, wmv = 0.f; int n = 0;
        if (p < cnt) {
            n = idx[s * CAP + p];
            float xv = x[n];
            float wl = sigmf(__fdividef(xv - mu_min[s], sd_min[s]));
            float wh = sigmf(__fdividef(mu_max[s] - xv, sd_max[s]));
            wmv = wl * wh;
            xi = __fdividef(xv - centres[s], fmaxf(scales[s], 1e-8f));
        }
        xi_s[t] = xi; wm_s[t] = wmv; nn_s[t] = n;
    }
    __syncthreads();

    // ---- layer 0: hbuf[0][p][v] = tanh(W0[v]*xi[p] + b0[v]) ----
    {
        int p  = (t & 15) | ((t >> 6) << 4);
        int cg = (t >> 4) & 3;
        float xi = xi_s[p];
        const float4* W04 = (const float4*)(W0 + s * WID);
        const float4* b04 = (const float4*)(b0 + s * WID);
        char* row = hbuf[0] + p * ROWB;
        #pragma unroll
        for (int k = 0; k < 4; ++k) {
            int v0 = cg * 8 + k * 32;
            float4 wa = W04[v0 / 4],     ba = b04[v0 / 4];
            float4 wb = W04[v0 / 4 + 1], bb = b04[v0 / 4 + 1];
            f16x8 hv;
            hv[0] = (_Float16)tanh5(fmaf(wa.x, xi, ba.x));
            hv[1] = (_Float16)tanh5(fmaf(wa.y, xi, ba.y));
            hv[2] = (_Float16)tanh5(fmaf(wa.z, xi, ba.z));
            hv[3] = (_Float16)tanh5(fmaf(wa.w, xi, ba.w));
            hv[4] = (_Float16)tanh5(fmaf(wb.x, xi, bb.x));
            hv[5] = (_Float16)tanh5(fmaf(wb.y, xi, bb.y));
            hv[6] = (_Float16)tanh5(fmaf(wb.z, xi, bb.z));
            hv[7] = (_Float16)tanh5(fmaf(wb.w, xi, bb.w));
            *(f16x8*)(row + v0 * 2) = hv;
        }
    }

    // ---- hidden layers via MFMA 16x16x32 f16, bias folded into acc init ----
    int lane = t & 63, w = t >> 6;
    int lr = lane & 15, lg = lane >> 4;
    int cur = 0;
    for (int l = 0; l < NHID; ++l) {
        __syncthreads();
        const f16x8* WFp = (const f16x8*)WF + (size_t)(s * NHID + l) * 2048;
        const float* bhp = bh + (s * NHID + l) * WID;
        f32x4 acc[2][4];
        #pragma unroll
        for (int i = 0; i < 2; ++i) {
            int v0 = (w * 2 + i) * 16 + lg * 4;
            f32x4 binit = *(const f32x4*)(bhp + v0);    // C reg r = row v0+r = bias fold
            #pragma unroll
            for (int j = 0; j < 4; ++j) acc[i][j] = binit;
        }
        const char* hb = hbuf[cur];
        #pragma unroll
        for (int kk = 0; kk < 4; ++kk) {
            f16x8 a0 = WFp[((w * 2 + 0) * 4 + kk) * 64 + lane];
            f16x8 a1 = WFp[((w * 2 + 1) * 4 + kk) * 64 + lane];
            #pragma unroll
            for (int pt = 0; pt < 4; ++pt) {
                f16x8 b = *(const f16x8*)(hb + (pt * 16 + lr) * ROWB + kk * 64 + lg * 16);
                acc[0][pt] = __builtin_amdgcn_mfma_f32_16x16x32_f16(a0, b, acc[0][pt], 0, 0, 0);
                acc[1][pt] = __builtin_amdgcn_mfma_f32_16x16x32_f16(a1, b, acc[1][pt], 0, 0, 0);
            }
        }
        char* ho = hbuf[cur ^ 1];
        #pragma unroll
        for (int i = 0; i < 2; ++i) {
            int v0 = (w * 2 + i) * 16 + lg * 4;
            #pragma unroll
            for (int pt = 0; pt < 4; ++pt) {
                f32x4 a = acc[i][pt];
                f16x4 qv;
                qv[0] = (_Float16)tanh5(a[0]);
                qv[1] = (_Float16)tanh5(a[1]);
                qv[2] = (_Float16)tanh5(a[2]);
                qv[3] = (_Float16)tanh5(a[3]);
                *(f16x4*)(ho + (pt * 16 + lr) * ROWB + v0 * 2) = qv;
            }
        }
        cur ^= 1;
    }
    __syncthreads();

    // ---- output layer: one row-0 A-frag MFMA per kk; wave w covers points w*16..w*16+15
    {
        const char* hf = hbuf[cur];
        float bo = bout[s];
        f32x4 oacc = (f32x4){bo, bo, bo, bo};
        const f16x8* WOp = (const f16x8*)WoutF + s * 256;
        #pragma unroll
        for (int kk = 0; kk < 4; ++kk) {
            f16x8 a = WOp[kk * 64 + lane];
            f16x8 b = *(const f16x8*)(hf + (w * 16 + lr) * ROWB + kk * 64 + lg * 16);
            oacc = __builtin_amdgcn_mfma_f32_16x16x32_f16(a, b, oacc, 0, 0, 0);
        }
        if (lg == 0) {                         // D row 0 lives in lanes 0..15, reg 0
            int p = w * 16 + lr;
            if (base + p < cnt) atomicAdd(&out[nn_s[p]], wm_s[p] * oacc[0]);
        }
    }
}

extern "C" void kernel_launch(void* const* d_in, const int* in_sizes, int n_in,
                              void* d_out, int out_size, void* d_ws, size_t ws_size,
                              hipStream_t stream) {
    const float* x       = (const float*)d_in[0];
    const float* W0      = (const float*)d_in[1];
    const float* b0      = (const float*)d_in[2];
    const float* Wh      = (const float*)d_in[3];
    const float* bh      = (const float*)d_in[4];
    const float* Wout    = (const float*)d_in[5];
    const float* bout    = (const float*)d_in[6];
    const float* centres = (const float*)d_in[7];
    const float* scales  = (const float*)d_in[8];
    const float* mu_min  = (const float*)d_in[9];
    const float* sd_min  = (const float*)d_in[10];
    const float* mu_max  = (const float*)d_in[11];
    const float* sd_max  = (const float*)d_in[12];
    float* out = (float*)d_out;
    char* ws = (char*)d_ws;
    int*      counts = (int*)ws;
    int*      idx    = (int*)(ws + OFF_IDX);
    _Float16* WF     = (_Float16*)(ws + OFF_WF);
    _Float16* WoutF  = (_Float16*)(ws + OFF_WO);

    init_kernel<<<dim3(656), dim3(256), 0, stream>>>(out, counts, Wh, WF, Wout, WoutF);
    bucket_kernel<<<dim3(NPTS / 256), dim3(256), 0, stream>>>(x, mu_min, sd_min, mu_max, sd_max,
                                                              counts, idx);
    dim3 grid(NS, CAP / 64);
    mlp_kernel<<<grid, dim3(256), 0, stream>>>(x, W0, b0, WF, bh, WoutF, bout,
                                               centres, scales, mu_min, sd_min, mu_max, sd_max,
                                               counts, idx, out);
}

// Round 4
// 139.266 us; speedup vs baseline: 2.3128x; 2.3128x over previous
//
#include <hip/hip_runtime.h>
#include <hip/hip_bf16.h>
#include <math.h>

#define NPTS   65536
#define NS     16
#define WID    128
#define NHID   3
#define CAP    24576
#define ROWB   272              // bytes per point-row in LDS h tile (128 f16 + 16B pad)
#define CZ     -25.33f          // ln(1e-11): drop (point,s) when min window logit below this
#define CSTR   32               // counts stride in ints (128 B -> one cache line per counter)

// ws layout:
//   [0, 2KB)                   counts[16] padded 128B apart
//   [OFF_IDX, +1.50MB)         idx buckets
//   [OFF_WF,  +1.50MB)         f16 hidden-weight MFMA fragments
//   [OFF_WO,  +64KB)           f16 output-weight row-0 MFMA fragments
#define OFF_IDX 2048
#define OFF_WF  (OFF_IDX + NS * CAP * 4)
#define OFF_WO  (OFF_WF + NS * NHID * WID * WID * 2)

typedef _Float16 f16x8 __attribute__((ext_vector_type(8)));
typedef _Float16 f16x4 __attribute__((ext_vector_type(4)));
typedef float    f32x4 __attribute__((ext_vector_type(4)));

// tanh(x) = 1 - 2/(exp2(x*2*log2e)+1); exp2 saturates cleanly so no clamp needed
__device__ __forceinline__ float tanh5(float x) {
    float e = __builtin_amdgcn_exp2f(x * 2.8853900817779268f);
    float r = __builtin_amdgcn_rcpf(e + 1.f);
    return fmaf(-2.f, r, 1.f);
}
__device__ __forceinline__ float sigmf(float z) {
    float e = __builtin_amdgcn_exp2f(-z * 1.4426950408889634f);
    return __builtin_amdgcn_rcpf(1.f + e);
}

// prepack WF (hidden) + WoutF (output row-0 frags) + zero padded counts
__global__ void init_kernel(int* __restrict__ counts,
                            const float* __restrict__ Wh, _Float16* __restrict__ WF,
                            const float* __restrict__ Wout, _Float16* __restrict__ WoutF) {
    int b = blockIdx.x, t = threadIdx.x;
    if (b == 0 && t < NS) counts[t * CSTR] = 0;
    if (b < 384) {
        // WF frag g = ((sl*8 + vt)*4 + kk)*64 + lane holds
        // Wh[sl][v = vt*16 + (lane&15)][w = kk*32 + (lane>>4)*8 .. +7]
        int g = b * 256 + t;
        int sl = g >> 11, r = g & 2047;
        int vt = r >> 8, kk = (r >> 6) & 3, lane = r & 63;
        int v = vt * 16 + (lane & 15);
        int w0 = kk * 32 + (lane >> 4) * 8;
        const float* src = Wh + (sl << 14) + v * WID + w0;
        float4 a = *(const float4*)src;
        float4 c = *(const float4*)(src + 4);
        f16x8 o;
        o[0] = (_Float16)a.x; o[1] = (_Float16)a.y; o[2] = (_Float16)a.z; o[3] = (_Float16)a.w;
        o[4] = (_Float16)c.x; o[5] = (_Float16)c.y; o[6] = (_Float16)c.z; o[7] = (_Float16)c.w;
        ((f16x8*)WF)[g] = o;
    } else {
        // WoutF frag g = (s*4 + kk)*64 + lane: A[row=lane&15][k=kk*32+(lane>>4)*8..+7],
        // only row 0 nonzero = Wout[s][k]
        int g = (b - 384) * 256 + t;          // 4096 frags
        int s = g >> 8, kk = (g >> 6) & 3, lane = g & 63;
        f16x8 o = (f16x8)(_Float16)0.f;
        if ((lane & 15) == 0) {
            int w0 = kk * 32 + (lane >> 4) * 8;
            const float* src = Wout + s * WID + w0;
            float4 a = *(const float4*)src;
            float4 c = *(const float4*)(src + 4);
            o[0] = (_Float16)a.x; o[1] = (_Float16)a.y; o[2] = (_Float16)a.z; o[3] = (_Float16)a.w;
            o[4] = (_Float16)c.x; o[5] = (_Float16)c.y; o[6] = (_Float16)c.z; o[7] = (_Float16)c.w;
        }
        ((f16x8*)WoutF)[g] = o;
    }
}

// hierarchical compaction: wave ballot -> LDS wave counts -> 1 global atomic per (block,s)
__global__ void bucket_kernel(const float* __restrict__ x,
                              const float* __restrict__ mu_min, const float* __restrict__ sd_min,
                              const float* __restrict__ mu_max, const float* __restrict__ sd_max,
                              int* counts, int* __restrict__ idx,
                              float* __restrict__ out) {
    __shared__ int wcnt[NS][4];
    __shared__ int wbase[NS][4];
    __shared__ int bbase[NS];
    int t = threadIdx.x, lane = t & 63, wid = t >> 6;
    int n = blockIdx.x * 256 + t;
    float xv = x[n];
    out[n] = 0.f;                       // fused out-zero (runs before any mlp launch)
    unsigned long long ltmask = (1ULL << lane) - 1ULL;
    unsigned mbits = 0;
    #pragma unroll
    for (int s = 0; s < NS; ++s) {
        float z1 = __fdividef(xv - mu_min[s], sd_min[s]);
        float z2 = __fdividef(mu_max[s] - xv, sd_max[s]);
        bool m = (z1 > CZ) && (z2 > CZ);
        mbits |= (unsigned)m << s;
        unsigned long long mk = __ballot(m);
        if (lane == 0) wcnt[s][wid] = __popcll(mk);
    }
    __syncthreads();
    if (t < NS) {
        int c0 = wcnt[t][0], c1 = wcnt[t][1], c2 = wcnt[t][2], c3 = wcnt[t][3];
        wbase[t][0] = 0; wbase[t][1] = c0; wbase[t][2] = c0 + c1; wbase[t][3] = c0 + c1 + c2;
        bbase[t] = atomicAdd(&counts[t * CSTR], c0 + c1 + c2 + c3);
    }
    __syncthreads();
    #pragma unroll
    for (int s = 0; s < NS; ++s) {
        bool m = (mbits >> s) & 1;
        unsigned long long mk = __ballot(m);
        if (m) {
            int pos = __popcll(mk & ltmask);
            int g = bbase[s] + wbase[s][wid] + pos;
            if (g < CAP) idx[s * CAP + g] = n;
        }
    }
}

__global__ __launch_bounds__(256, 4) void mlp_kernel(
        const float* __restrict__ x,
        const float* __restrict__ W0,   const float* __restrict__ b0,
        const _Float16* __restrict__ WF, const float* __restrict__ bh,
        const _Float16* __restrict__ WoutF, const float* __restrict__ bout,
        const float* __restrict__ centres, const float* __restrict__ scales,
        const float* __restrict__ mu_min,  const float* __restrict__ sd_min,
        const float* __restrict__ mu_max,  const float* __restrict__ sd_max,
        const int* __restrict__ counts, const int* __restrict__ idx,
        float* __restrict__ out) {
    __shared__ __align__(16) char hbuf[2][64 * ROWB];   // ping-pong [p][v] f16, 272B rows
    __shared__ float xi_s[64], wm_s[64];
    __shared__ int   nn_s[64];

    int s = blockIdx.x;
    int cnt = counts[s * CSTR]; if (cnt > CAP) cnt = CAP;
    int base = blockIdx.y * 64;
    if (base >= cnt) return;               // uniform early-out before any barrier
    int t = threadIdx.x;

    if (t < 64) {
        int p = base + t;
        float xi = 0.f, wmv = 0.f; int n = 0;
        if (p < cnt) {
            n = idx[s * CAP + p];
            float xv = x[n];
            float wl = sigmf(__fdividef(xv - mu_min[s], sd_min[s]));
            float wh = sigmf(__fdividef(mu_max[s] - xv, sd_max[s]));
            wmv = wl * wh;
            xi = __fdividef(xv - centres[s], fmaxf(scales[s], 1e-8f));
        }
        xi_s[t] = xi; wm_s[t] = wmv; nn_s[t] = n;
    }
    __syncthreads();

    // ---- layer 0: hbuf[0][p][v] = tanh(W0[v]*xi[p] + b0[v]) ----
    {
        int p  = (t & 15) | ((t >> 6) << 4);
        int cg = (t >> 4) & 3;
        float xi = xi_s[p];
        const float4* W04 = (const float4*)(W0 + s * WID);
        const float4* b04 = (const float4*)(b0 + s * WID);
        char* row = hbuf[0] + p * ROWB;
        #pragma unroll
        for (int k = 0; k < 4; ++k) {
            int v0 = cg * 8 + k * 32;
            float4 wa = W04[v0 / 4],     ba = b04[v0 / 4];
            float4 wb = W04[v0 / 4 + 1], bb = b04[v0 / 4 + 1];
            f16x8 hv;
            hv[0] = (_Float16)tanh5(fmaf(wa.x, xi, ba.x));
            hv[1] = (_Float16)tanh5(fmaf(wa.y, xi, ba.y));
            hv[2] = (_Float16)tanh5(fmaf(wa.z, xi, ba.z));
            hv[3] = (_Float16)tanh5(fmaf(wa.w, xi, ba.w));
            hv[4] = (_Float16)tanh5(fmaf(wb.x, xi, bb.x));
            hv[5] = (_Float16)tanh5(fmaf(wb.y, xi, bb.y));
            hv[6] = (_Float16)tanh5(fmaf(wb.z, xi, bb.z));
            hv[7] = (_Float16)tanh5(fmaf(wb.w, xi, bb.w));
            *(f16x8*)(row + v0 * 2) = hv;
        }
    }

    // ---- hidden layers via MFMA 16x16x32 f16, bias folded into acc init ----
    int lane = t & 63, w = t >> 6;
    int lr = lane & 15, lg = lane >> 4;
    int cur = 0;
    for (int l = 0; l < NHID; ++l) {
        __syncthreads();
        const f16x8* WFp = (const f16x8*)WF + (size_t)(s * NHID + l) * 2048;
        const float* bhp = bh + (s * NHID + l) * WID;
        f32x4 acc[2][4];
        #pragma unroll
        for (int i = 0; i < 2; ++i) {
            int v0 = (w * 2 + i) * 16 + lg * 4;
            f32x4 binit = *(const f32x4*)(bhp + v0);    // C reg r = row v0+r = bias fold
            #pragma unroll
            for (int j = 0; j < 4; ++j) acc[i][j] = binit;
        }
        const char* hb = hbuf[cur];
        #pragma unroll
        for (int kk = 0; kk < 4; ++kk) {
            f16x8 a0 = WFp[((w * 2 + 0) * 4 + kk) * 64 + lane];
            f16x8 a1 = WFp[((w * 2 + 1) * 4 + kk) * 64 + lane];
            #pragma unroll
            for (int pt = 0; pt < 4; ++pt) {
                f16x8 b = *(const f16x8*)(hb + (pt * 16 + lr) * ROWB + kk * 64 + lg * 16);
                acc[0][pt] = __builtin_amdgcn_mfma_f32_16x16x32_f16(a0, b, acc[0][pt], 0, 0, 0);
                acc[1][pt] = __builtin_amdgcn_mfma_f32_16x16x32_f16(a1, b, acc[1][pt], 0, 0, 0);
            }
        }
        char* ho = hbuf[cur ^ 1];
        #pragma unroll
        for (int i = 0; i < 2; ++i) {
            int v0 = (w * 2 + i) * 16 + lg * 4;
            #pragma unroll
            for (int pt = 0; pt < 4; ++pt) {
                f32x4 a = acc[i][pt];
                f16x4 qv;
                qv[0] = (_Float16)tanh5(a[0]);
                qv[1] = (_Float16)tanh5(a[1]);
                qv[2] = (_Float16)tanh5(a[2]);
                qv[3] = (_Float16)tanh5(a[3]);
                *(f16x4*)(ho + (pt * 16 + lr) * ROWB + v0 * 2) = qv;
            }
        }
        cur ^= 1;
    }
    __syncthreads();

    // ---- output layer: one row-0 A-frag MFMA per kk; wave w covers points w*16..w*16+15
    {
        const char* hf = hbuf[cur];
        float bo = bout[s];
        f32x4 oacc = (f32x4){bo, bo, bo, bo};
        const f16x8* WOp = (const f16x8*)WoutF + s * 256;
        #pragma unroll
        for (int kk = 0; kk < 4; ++kk) {
            f16x8 a = WOp[kk * 64 + lane];
            f16x8 b = *(const f16x8*)(hf + (w * 16 + lr) * ROWB + kk * 64 + lg * 16);
            oacc = __builtin_amdgcn_mfma_f32_16x16x32_f16(a, b, oacc, 0, 0, 0);
        }
        if (lg == 0) {                         // D row 0 lives in lanes 0..15, reg 0
            int p = w * 16 + lr;
            if (base + p < cnt) atomicAdd(&out[nn_s[p]], wm_s[p] * oacc[0]);
        }
    }
}

extern "C" void kernel_launch(void* const* d_in, const int* in_sizes, int n_in,
                              void* d_out, int out_size, void* d_ws, size_t ws_size,
                              hipStream_t stream) {
    const float* x       = (const float*)d_in[0];
    const float* W0      = (const float*)d_in[1];
    const float* b0      = (const float*)d_in[2];
    const float* Wh      = (const float*)d_in[3];
    const float* bh      = (const float*)d_in[4];
    const float* Wout    = (const float*)d_in[5];
    const float* bout    = (const float*)d_in[6];
    const float* centres = (const float*)d_in[7];
    const float* scales  = (const float*)d_in[8];
    const float* mu_min  = (const float*)d_in[9];
    const float* sd_min  = (const float*)d_in[10];
    const float* mu_max  = (const float*)d_in[11];
    const float* sd_max  = (const float*)d_in[12];
    float* out = (float*)d_out;
    char* ws = (char*)d_ws;
    int*      counts = (int*)ws;
    int*      idx    = (int*)(ws + OFF_IDX);
    _Float16* WF     = (_Float16*)(ws + OFF_WF);
    _Float16* WoutF  = (_Float16*)(ws + OFF_WO);

    init_kernel<<<dim3(400), dim3(256), 0, stream>>>(counts, Wh, WF, Wout, WoutF);
    bucket_kernel<<<dim3(NPTS / 256), dim3(256), 0, stream>>>(x, mu_min, sd_min, mu_max, sd_max,
                                                              counts, idx, out);
    dim3 grid(NS, CAP / 64);
    mlp_kernel<<<grid, dim3(256), 0, stream>>>(x, W0, b0, WF, bh, WoutF, bout,
                                               centres, scales, mu_min, sd_min, mu_max, sd_max,
                                               counts, idx, out);
}